// Round 1
// baseline (1202.435 us; speedup 1.0000x reference)
//
#include <hip/hip_runtime.h>

namespace {
constexpr int B    = 32;
constexpr int CIN  = 64;
constexpr int H    = 128;
constexpr int L    = 4096;
constexpr int TL   = 96;            // output positions per tile
constexpr int PPAD = 128;           // LDS columns (30 halo + 96 + 2 pad)
constexpr int NCOL = 30 + TL;       // 126 valid columns
constexpr int NTILES = (L + TL - 1) / TL;  // 43
constexpr float EPS = 1e-5f;
}

__global__ __launch_bounds__(512, 4) void tcn_fused(
    const float* __restrict__ x,
    const float* __restrict__ sc_w,
    const float* __restrict__ pw_w0,
    const float* __restrict__ pw_w_rest,
    const float* __restrict__ pw_b,
    const float* __restrict__ bn_g,
    const float* __restrict__ bn_b,
    const float* __restrict__ bn_m,
    const float* __restrict__ bn_v,
    const float* __restrict__ res_w,
    const float* __restrict__ res_b,
    const float* __restrict__ out_w,
    const float* __restrict__ out_b,
    float* __restrict__ out)
{
    __shared__ float buf[H][PPAD];   // 64 KB -> 2 blocks/CU

    const int tile = blockIdx.x;
    const int b    = blockIdx.y;
    const int s    = tile * TL;
    const int tid  = threadIdx.x;
    const int lane = tid & 63;
    const int wave = tid >> 6;

    // ---- stage x[b, 0:64, s-30 : s+98) into rows [0,64), cols [0,128) ----
    const float* xb = x + (size_t)b * CIN * L;
    #pragma unroll
    for (int it = 0; it < (CIN * PPAD) / 512; ++it) {
        const int idx = it * 512 + tid;
        const int c = idx >> 7;          // /PPAD
        const int j = idx & (PPAD - 1);
        const int p = s - 30 + j;
        float v = 0.0f;                   // causal left pad = 0
        if (p >= 0)
            v = xb[(size_t)c * L + (p < L ? p : L - 1)];  // right clamp: tail garbage masked later
        buf[c][j] = v;
    }
    __syncthreads();

    // wave task: obase = 32-channel block, pb = 64-position block
    int obase = (wave & 3) << 5;
    obase = __builtin_amdgcn_readfirstlane(obase);   // force SGPR -> s_load for W
    const int pb = wave >> 2;

    // =================== layer 0 (K=64, dil=1, j0=2) + residual 1x1 ===================
    {
        const float w0 = sc_w[0], w1 = sc_w[1], w2 = sc_w[2];
        const int j = 2 + pb * 64 + lane;
        const bool active = (j < NCOL);
        const int jc = active ? j : (NCOL - 1);

        float accY[32], accR[32];
        #pragma unroll
        for (int oo = 0; oo < 32; ++oo) { accY[oo] = 0.0f; accR[oo] = 0.0f; }

        for (int c = 0; c < CIN; ++c) {
            const float t0 = buf[c][jc];
            const float t1 = buf[c][jc - 1];
            const float t2 = buf[c][jc - 2];
            const float d  = fmaf(w2, t0, fmaf(w1, t1, w0 * t2));
            const float* wy = pw_w0 + obase * CIN + c;   // uniform -> scalar loads
            const float* wr = res_w + obase * CIN + c;
            #pragma unroll
            for (int oo = 0; oo < 32; ++oo) {
                accY[oo] = fmaf(wy[oo * CIN], d,  accY[oo]);
                accR[oo] = fmaf(wr[oo * CIN], t0, accR[oo]);
            }
        }
        #pragma unroll
        for (int oo = 0; oo < 32; ++oo) {
            const int o = obase + oo;
            const float A  = bn_g[o] * rsqrtf(bn_v[o] + EPS);
            const float Cc = fmaf(A, pw_b[o] - bn_m[o], bn_b[o]);
            const float y  = fmaxf(fmaf(A, accY[oo], Cc), 0.0f);
            const float r  = accR[oo] + res_b[o];
            accY[oo] = fmaxf(y + r, 0.0f);
        }
        __syncthreads();                 // all reads of x done
        if (active) {
            #pragma unroll
            for (int oo = 0; oo < 32; ++oo) buf[obase + oo][j] = accY[oo];
        }
        __syncthreads();                 // h1 visible
    }

    // =================== layers 1..3 (K=128, dil=2^li, j0=4<<li - 2) ===================
    #pragma unroll
    for (int li = 1; li < 4; ++li) {
        const int dil = 1 << li;
        const int j0  = (4 << li) - 2;   // 6, 14, 30
        const float w0 = sc_w[li * 3 + 0], w1 = sc_w[li * 3 + 1], w2 = sc_w[li * 3 + 2];
        const float* W = pw_w_rest + (size_t)(li - 1) * H * H;
        const int j = j0 + pb * 64 + lane;
        const bool active = (j < NCOL);
        const int jc = active ? j : (NCOL - 1);

        float acc[32];
        #pragma unroll
        for (int oo = 0; oo < 32; ++oo) acc[oo] = 0.0f;

        for (int c = 0; c < H; ++c) {
            const float t0 = buf[c][jc];
            const float t1 = buf[c][jc - dil];
            const float t2 = buf[c][jc - 2 * dil];
            const float d  = fmaf(w2, t0, fmaf(w1, t1, w0 * t2));
            const float* wp = W + obase * H + c;         // uniform -> scalar loads
            #pragma unroll
            for (int oo = 0; oo < 32; ++oo)
                acc[oo] = fmaf(wp[oo * H], d, acc[oo]);
        }
        #pragma unroll
        for (int oo = 0; oo < 32; ++oo) {
            const int o = obase + oo;
            const float A  = bn_g[li * H + o] * rsqrtf(bn_v[li * H + o] + EPS);
            const float Cc = fmaf(A, pw_b[li * H + o] - bn_m[li * H + o], bn_b[li * H + o]);
            const float y  = fmaxf(fmaf(A, acc[oo], Cc), 0.0f);
            const float r  = buf[o][jc];                 // identity residual (read pre-overwrite)
            acc[oo] = fmaxf(y + r, 0.0f);
        }
        __syncthreads();                 // all reads of h_{li} done
        if (active) {
            #pragma unroll
            for (int oo = 0; oo < 32; ++oo) buf[obase + oo][j] = acc[oo];
        }
        __syncthreads();                 // h_{li+1} visible
    }

    // =================== output projection: out[b, 0, p] = out_w . h4[:, p] + out_b ===================
    if (tid < TL) {
        const int p = s + tid;
        if (p < L) {
            float a0 = 0.0f, a1 = 0.0f, a2 = 0.0f, a3 = 0.0f;
            #pragma unroll
            for (int o = 0; o < H; o += 4) {
                a0 = fmaf(out_w[o + 0], buf[o + 0][30 + tid], a0);
                a1 = fmaf(out_w[o + 1], buf[o + 1][30 + tid], a1);
                a2 = fmaf(out_w[o + 2], buf[o + 2][30 + tid], a2);
                a3 = fmaf(out_w[o + 3], buf[o + 3][30 + tid], a3);
            }
            out[(size_t)b * L + p] = ((a0 + a1) + (a2 + a3)) + out_b[0];
        }
    }
}

extern "C" void kernel_launch(void* const* d_in, const int* in_sizes, int n_in,
                              void* d_out, int out_size, void* d_ws, size_t ws_size,
                              hipStream_t stream) {
    const float* x         = (const float*)d_in[0];
    const float* sc_w      = (const float*)d_in[1];
    const float* pw_w0     = (const float*)d_in[2];
    const float* pw_w_rest = (const float*)d_in[3];
    const float* pw_b      = (const float*)d_in[4];
    const float* bn_g      = (const float*)d_in[5];
    const float* bn_b      = (const float*)d_in[6];
    const float* bn_m      = (const float*)d_in[7];
    const float* bn_v      = (const float*)d_in[8];
    const float* res_w     = (const float*)d_in[9];
    const float* res_b     = (const float*)d_in[10];
    const float* out_w     = (const float*)d_in[11];
    const float* out_b     = (const float*)d_in[12];
    float* out = (float*)d_out;

    dim3 grid(NTILES, B);
    tcn_fused<<<grid, 512, 0, stream>>>(x, sc_w, pw_w0, pw_w_rest, pw_b,
                                        bn_g, bn_b, bn_m, bn_v,
                                        res_w, res_b, out_w, out_b, out);
}

// Round 2
// 344.805 us; speedup vs baseline: 3.4873x; 3.4873x over previous
//
#include <hip/hip_runtime.h>

namespace {
constexpr int B    = 32;
constexpr int CIN  = 64;
constexpr int H    = 128;
constexpr int L    = 4096;
constexpr int TL   = 96;            // output positions per tile
constexpr int PPAD = 128;           // LDS columns (30 halo + 96 + 2 pad)
constexpr int NCOL = 30 + TL;       // 126 valid columns
constexpr int NTILES = (L + TL - 1) / TL;  // 43
constexpr float EPS = 1e-5f;
}

__global__ __launch_bounds__(512, 4) void tcn_fused(
    const float* __restrict__ x,
    const float* __restrict__ sc_w,
    const float* __restrict__ pw_w0,
    const float* __restrict__ pw_w_rest,
    const float* __restrict__ pw_b,
    const float* __restrict__ bn_g,
    const float* __restrict__ bn_b,
    const float* __restrict__ bn_m,
    const float* __restrict__ bn_v,
    const float* __restrict__ res_w,
    const float* __restrict__ res_b,
    const float* __restrict__ out_w,
    const float* __restrict__ out_b,
    float* __restrict__ out)
{
    __shared__ float buf[H][PPAD];   // 64 KB -> 2 blocks/CU (16 waves/CU)

    const int tile = blockIdx.x;
    const int b    = blockIdx.y;
    const int s    = tile * TL;
    const int tid  = threadIdx.x;
    const int lane = tid & 63;
    const int wave = tid >> 6;

    // ---- stage x[b, 0:64, s-30 : s+98) into rows [0,64), cols [0,128) ----
    const float* xb = x + (size_t)b * CIN * L;
    #pragma unroll
    for (int it = 0; it < (CIN * PPAD) / 512; ++it) {
        const int idx = it * 512 + tid;
        const int c = idx >> 7;
        const int j = idx & (PPAD - 1);
        const int p = s - 30 + j;
        float v = 0.0f;                               // causal left pad = 0
        if (p >= 0)
            v = xb[(size_t)c * L + (p < L ? p : L - 1)];  // right-clamp garbage masked at output
        buf[c][j] = v;
    }
    __syncthreads();

    // wave task: 16 output channels per wave, lanes = positions, 2 column-halves
    const int obase = __builtin_amdgcn_readfirstlane(wave << 4);

    // =================== layer 0 (CIN=64, dil=1, j0=2) + residual 1x1 ===================
    {
        const float w0 = sc_w[0], w1 = sc_w[1], w2 = sc_w[2];
        const int jA = 2 + lane;                      // always < 126
        const int jB = 66 + lane;
        const bool aB = (jB < NCOL);
        const int jcB = aB ? jB : (NCOL - 1);

        float acc[16][2], accR[16][2];
        #pragma unroll
        for (int q = 0; q < 16; ++q) {
            acc[q][0] = 0.f; acc[q][1] = 0.f;
            accR[q][0] = 0.f; accR[q][1] = 0.f;
        }

        for (int c4 = 0; c4 < CIN / 4; ++c4) {
            float d[4][2], t0v[4][2];
            #pragma unroll
            for (int k = 0; k < 4; ++k) {
                const int c = c4 * 4 + k;
                {
                    const float t0 = buf[c][jA], t1 = buf[c][jA - 1], t2 = buf[c][jA - 2];
                    t0v[k][0] = t0;
                    d[k][0] = fmaf(w2, t0, fmaf(w1, t1, w0 * t2));
                }
                {
                    const float t0 = buf[c][jcB], t1 = buf[c][jcB - 1], t2 = buf[c][jcB - 2];
                    t0v[k][1] = t0;
                    d[k][1] = fmaf(w2, t0, fmaf(w1, t1, w0 * t2));
                }
            }
            #pragma unroll
            for (int g = 0; g < 2; ++g) {                       // 8-row W groups: <=32 live SGPRs
                const int ob = g * 8;
                float4 wv[8];
                #pragma unroll
                for (int q = 0; q < 8; ++q)
                    wv[q] = *(const float4*)(pw_w0 + (size_t)(obase + ob + q) * CIN + c4 * 4);
                #pragma unroll
                for (int q = 0; q < 8; ++q) {
                    #pragma unroll
                    for (int ph = 0; ph < 2; ++ph) {
                        float a = acc[ob + q][ph];
                        a = fmaf(wv[q].x, d[0][ph], a);
                        a = fmaf(wv[q].y, d[1][ph], a);
                        a = fmaf(wv[q].z, d[2][ph], a);
                        a = fmaf(wv[q].w, d[3][ph], a);
                        acc[ob + q][ph] = a;
                    }
                }
            }
            #pragma unroll
            for (int g = 0; g < 2; ++g) {
                const int ob = g * 8;
                float4 rv[8];
                #pragma unroll
                for (int q = 0; q < 8; ++q)
                    rv[q] = *(const float4*)(res_w + (size_t)(obase + ob + q) * CIN + c4 * 4);
                #pragma unroll
                for (int q = 0; q < 8; ++q) {
                    #pragma unroll
                    for (int ph = 0; ph < 2; ++ph) {
                        float a = accR[ob + q][ph];
                        a = fmaf(rv[q].x, t0v[0][ph], a);
                        a = fmaf(rv[q].y, t0v[1][ph], a);
                        a = fmaf(rv[q].z, t0v[2][ph], a);
                        a = fmaf(rv[q].w, t0v[3][ph], a);
                        accR[ob + q][ph] = a;
                    }
                }
            }
        }
        #pragma unroll
        for (int q = 0; q < 16; ++q) {
            const int o = obase + q;
            const float A  = bn_g[o] * rsqrtf(bn_v[o] + EPS);
            const float Cc = fmaf(A, pw_b[o] - bn_m[o], bn_b[o]);
            const float y0 = fmaxf(fmaf(A, acc[q][0], Cc), 0.0f);
            const float y1 = fmaxf(fmaf(A, acc[q][1], Cc), 0.0f);
            float v0 = fmaxf(y0 + accR[q][0] + res_b[o], 0.0f);
            float v1 = fmaxf(y1 + accR[q][1] + res_b[o], 0.0f);
            if (s - 30 + jA < 0) v0 = 0.0f;            // true causal zero-padding (tile 0)
            acc[q][0] = v0;
            acc[q][1] = v1;                            // jB>=66 -> p>=36 always
        }
        __syncthreads();
        #pragma unroll
        for (int q = 0; q < 16; ++q) buf[obase + q][jA] = acc[q][0];
        if (aB) {
            #pragma unroll
            for (int q = 0; q < 16; ++q) buf[obase + q][jB] = acc[q][1];
        }
        __syncthreads();
    }

    // =================== layers 1..3 (C=128, dil=2^li, j0=4<<li - 2) ===================
    #pragma unroll
    for (int li = 1; li < 4; ++li) {
        const int dil = 1 << li;
        const int j0  = (4 << li) - 2;                // 6, 14, 30
        const float w0 = sc_w[li * 3 + 0], w1 = sc_w[li * 3 + 1], w2 = sc_w[li * 3 + 2];
        const float* __restrict__ W = pw_w_rest + (size_t)(li - 1) * H * H;
        const int jA = j0 + lane;                     // j0+63 <= 93 < 126 always
        const int jB = j0 + 64 + lane;
        const bool aB = (jB < NCOL);
        const int jcB = aB ? jB : (NCOL - 1);

        float acc[16][2];
        #pragma unroll
        for (int q = 0; q < 16; ++q) { acc[q][0] = 0.f; acc[q][1] = 0.f; }

        for (int c4 = 0; c4 < H / 4; ++c4) {
            float d[4][2];
            #pragma unroll
            for (int k = 0; k < 4; ++k) {
                const int c = c4 * 4 + k;
                {
                    const float t0 = buf[c][jA], t1 = buf[c][jA - dil], t2 = buf[c][jA - 2 * dil];
                    d[k][0] = fmaf(w2, t0, fmaf(w1, t1, w0 * t2));
                }
                {
                    const float t0 = buf[c][jcB], t1 = buf[c][jcB - dil], t2 = buf[c][jcB - 2 * dil];
                    d[k][1] = fmaf(w2, t0, fmaf(w1, t1, w0 * t2));
                }
            }
            #pragma unroll
            for (int g = 0; g < 2; ++g) {
                const int ob = g * 8;
                float4 wv[8];
                #pragma unroll
                for (int q = 0; q < 8; ++q)
                    wv[q] = *(const float4*)(W + (size_t)(obase + ob + q) * H + c4 * 4);
                #pragma unroll
                for (int q = 0; q < 8; ++q) {
                    #pragma unroll
                    for (int ph = 0; ph < 2; ++ph) {
                        float a = acc[ob + q][ph];
                        a = fmaf(wv[q].x, d[0][ph], a);
                        a = fmaf(wv[q].y, d[1][ph], a);
                        a = fmaf(wv[q].z, d[2][ph], a);
                        a = fmaf(wv[q].w, d[3][ph], a);
                        acc[ob + q][ph] = a;
                    }
                }
            }
        }
        // residual (identity) — read before overwrite
        float rA[16], rB[16];
        #pragma unroll
        for (int q = 0; q < 16; ++q) {
            rA[q] = buf[obase + q][jA];
            rB[q] = buf[obase + q][jcB];
        }
        #pragma unroll
        for (int q = 0; q < 16; ++q) {
            const int o = obase + q;
            const float A  = bn_g[li * H + o] * rsqrtf(bn_v[li * H + o] + EPS);
            const float Cc = fmaf(A, pw_b[li * H + o] - bn_m[li * H + o], bn_b[li * H + o]);
            const float y0 = fmaxf(fmaf(A, acc[q][0], Cc), 0.0f);
            const float y1 = fmaxf(fmaf(A, acc[q][1], Cc), 0.0f);
            float v0 = fmaxf(y0 + rA[q], 0.0f);
            float v1 = fmaxf(y1 + rB[q], 0.0f);
            if (s - 30 + jA < 0) v0 = 0.0f;            // zero halo for p<0 (tile 0 only)
            acc[q][0] = v0;
            acc[q][1] = v1;
        }
        __syncthreads();
        #pragma unroll
        for (int q = 0; q < 16; ++q) buf[obase + q][jA] = acc[q][0];
        if (aB) {
            #pragma unroll
            for (int q = 0; q < 16; ++q) buf[obase + q][jB] = acc[q][1];
        }
        __syncthreads();
    }

    // =================== output projection ===================
    if (tid < TL) {
        const int p = s + tid;
        if (p < L) {
            float a0 = 0.0f, a1 = 0.0f, a2 = 0.0f, a3 = 0.0f;
            #pragma unroll
            for (int o = 0; o < H; o += 4) {
                a0 = fmaf(out_w[o + 0], buf[o + 0][30 + tid], a0);
                a1 = fmaf(out_w[o + 1], buf[o + 1][30 + tid], a1);
                a2 = fmaf(out_w[o + 2], buf[o + 2][30 + tid], a2);
                a3 = fmaf(out_w[o + 3], buf[o + 3][30 + tid], a3);
            }
            out[(size_t)b * L + p] = ((a0 + a1) + (a2 + a3)) + out_b[0];
        }
    }
}

extern "C" void kernel_launch(void* const* d_in, const int* in_sizes, int n_in,
                              void* d_out, int out_size, void* d_ws, size_t ws_size,
                              hipStream_t stream) {
    const float* x         = (const float*)d_in[0];
    const float* sc_w      = (const float*)d_in[1];
    const float* pw_w0     = (const float*)d_in[2];
    const float* pw_w_rest = (const float*)d_in[3];
    const float* pw_b      = (const float*)d_in[4];
    const float* bn_g      = (const float*)d_in[5];
    const float* bn_b      = (const float*)d_in[6];
    const float* bn_m      = (const float*)d_in[7];
    const float* bn_v      = (const float*)d_in[8];
    const float* res_w     = (const float*)d_in[9];
    const float* res_b     = (const float*)d_in[10];
    const float* out_w     = (const float*)d_in[11];
    const float* out_b     = (const float*)d_in[12];
    float* out = (float*)d_out;

    dim3 grid(NTILES, B);
    tcn_fused<<<grid, 512, 0, stream>>>(x, sc_w, pw_w0, pw_w_rest, pw_b,
                                        bn_g, bn_b, bn_m, bn_v,
                                        res_w, res_b, out_w, out_b, out);
}